// Round 1
// baseline (147.432 us; speedup 1.0000x reference)
//
#include <hip/hip_runtime.h>
#include <hip/hip_bf16.h>

#define NROWS 8192
#define DIM   256
#define EPSV  1e-6f
#define BM    128
#define BN    128
#define BK    32

typedef __bf16 bf16x8 __attribute__((ext_vector_type(8)));
typedef float  f32x4  __attribute__((ext_vector_type(4)));

// ---------------------------------------------------------------------------
// Kernel 1: row-normalize, emit bf16(e) + s[i]=sum(e*e), r[i]=sum(e)
// One wave (64 lanes) per row; lane handles 4 consecutive floats.
// ---------------------------------------------------------------------------
__global__ __launch_bounds__(256) void normalize_kernel(
    const float* __restrict__ emb, __bf16* __restrict__ Ebf,
    float* __restrict__ s_out, float* __restrict__ r_out)
{
    const int wave = threadIdx.x >> 6;
    const int lane = threadIdx.x & 63;
    const int row  = blockIdx.x * 4 + wave;

    const float4 v = ((const float4*)(emb + row * DIM))[lane];
    float ss = v.x*v.x + v.y*v.y + v.z*v.z + v.w*v.w;
    #pragma unroll
    for (int off = 32; off; off >>= 1) ss += __shfl_xor(ss, off);

    const float inv = 1.0f / fmaxf(sqrtf(ss), EPSV);
    float4 e; e.x = v.x*inv; e.y = v.y*inv; e.z = v.z*inv; e.w = v.w*inv;

    float sp = e.x*e.x + e.y*e.y + e.z*e.z + e.w*e.w;
    float rp = e.x + e.y + e.z + e.w;
    #pragma unroll
    for (int off = 32; off; off >>= 1) {
        sp += __shfl_xor(sp, off);
        rp += __shfl_xor(rp, off);
    }

    union { __bf16 h[4]; uint2 u; } pk;
    pk.h[0] = (__bf16)e.x; pk.h[1] = (__bf16)e.y;
    pk.h[2] = (__bf16)e.z; pk.h[3] = (__bf16)e.w;
    *(uint2*)(Ebf + row * DIM + lane * 4) = pk.u;

    if (lane == 0) { s_out[row] = sp; r_out[row] = rp; }
}

// ---------------------------------------------------------------------------
// Kernel 2: lower-triangle 128x128 MFMA tiles of G = E_bf16 * E_bf16^T,
// fused loss epilogue, block reduce, one atomicAdd per block.
// ---------------------------------------------------------------------------
__global__ __launch_bounds__(256) void loss_kernel(
    const __bf16* __restrict__ Ebf,
    const float* __restrict__ s_arr, const float* __restrict__ r_arr,
    const int* __restrict__ lab, float* __restrict__ out)
{
    const int bi = blockIdx.x, bj = blockIdx.y;
    if (bi < bj) return;   // uniform per block: whole block exits together

    __shared__ __align__(16) __bf16 As[BM * BK];
    __shared__ __align__(16) __bf16 Bs[BN * BK];
    __shared__ float sI[BM], rI[BM], sJ[BN], rJ[BN];
    __shared__ int   lI[BM], lJ[BN];
    __shared__ float wsum[4];

    const int tid  = threadIdx.x;
    const int wave = tid >> 6;
    const int lane = tid & 63;
    const int i0 = bi * BM, j0 = bj * BN;

    if (tid < 128) {
        sI[tid] = s_arr[i0 + tid]; rI[tid] = r_arr[i0 + tid]; lI[tid] = lab[i0 + tid];
        sJ[tid] = s_arr[j0 + tid]; rJ[tid] = r_arr[j0 + tid]; lJ[tid] = lab[j0 + tid];
    }

    f32x4 acc[4][4] = {};           // acc[fa][fb]: 4x4 frags of 16x16 per wave
    const int wm = wave >> 1, wn = wave & 1;
    const int quad = lane >> 4, mlane = lane & 15;

    #pragma unroll 1
    for (int kt = 0; kt < DIM / BK; ++kt) {
        const int k0 = kt * BK;
        // stage A/B tiles: 512 chunks of 8 bf16 each; thread does chunks tid, tid+256
        #pragma unroll
        for (int rr = 0; rr < 2; ++rr) {
            const int c   = tid + rr * 256;
            const int row = c >> 2;
            const int col = (c & 3) * 8;
            *(uint4*)(As + row * BK + col) =
                *(const uint4*)(Ebf + (size_t)(i0 + row) * DIM + k0 + col);
            *(uint4*)(Bs + row * BK + col) =
                *(const uint4*)(Ebf + (size_t)(j0 + row) * DIM + k0 + col);
        }
        __syncthreads();

        bf16x8 af[4], bfr[4];
        #pragma unroll
        for (int f = 0; f < 4; ++f) {
            af[f]  = *(const bf16x8*)(As + (wm * 64 + f * 16 + mlane) * BK + quad * 8);
            bfr[f] = *(const bf16x8*)(Bs + (wn * 64 + f * 16 + mlane) * BK + quad * 8);
        }
        #pragma unroll
        for (int fa = 0; fa < 4; ++fa)
            #pragma unroll
            for (int fb = 0; fb < 4; ++fb)
                acc[fa][fb] = __builtin_amdgcn_mfma_f32_16x16x32_bf16(
                    af[fa], bfr[fb], acc[fa][fb], 0, 0, 0);
        __syncthreads();
    }

    // Epilogue. C/D layout (verified, m89/m91): col = lane&15, row = (lane>>4)*4 + reg
    float lsum = 0.0f;
    #pragma unroll
    for (int fa = 0; fa < 4; ++fa) {
        #pragma unroll
        for (int reg = 0; reg < 4; ++reg) {
            const int il = wm * 64 + fa * 16 + quad * 4 + reg;
            const int gi = i0 + il;
            const float si = sI[il], ri = rI[il];
            const int   li = lI[il];
            #pragma unroll
            for (int fb = 0; fb < 4; ++fb) {
                const int jl = wn * 64 + fb * 16 + mlane;
                const int gj = j0 + jl;
                if (gi > gj) {
                    const float g  = acc[fa][fb][reg];
                    float d2 = si + sJ[jl] - 2.0f * g
                             + 2.0f * EPSV * (ri - rJ[jl])
                             + (float)DIM * EPSV * EPSV;
                    const float dist = sqrtf(fmaxf(d2, 1e-12f));
                    float loss;
                    if (li == lJ[jl]) {
                        const float t = fmaxf(dist - 0.1f, 0.0f);
                        loss = 0.5f * t * t;
                    } else {
                        const float t = fmaxf(1.0f - dist, 0.0f);
                        const float boost = (gi == gj + 1 && li == 1) ? 2.0f : 1.0f;
                        loss = 0.5f * boost * t * t;
                    }
                    lsum += loss;
                }
            }
        }
    }

    #pragma unroll
    for (int off = 32; off; off >>= 1) lsum += __shfl_down(lsum, off);
    if (lane == 0) wsum[wave] = lsum;
    __syncthreads();
    if (tid == 0) {
        const float bs = wsum[0] + wsum[1] + wsum[2] + wsum[3];
        const float scale = 1.0f / 33550336.0f;   // n*(n-1)/2 = 8192*8191/2
        atomicAdd(out, bs * scale);
    }
}

// ---------------------------------------------------------------------------
extern "C" void kernel_launch(void* const* d_in, const int* in_sizes, int n_in,
                              void* d_out, int out_size, void* d_ws, size_t ws_size,
                              hipStream_t stream)
{
    const float* emb = (const float*)d_in[0];
    const int*   lab = (const int*)d_in[1];
    float*       out = (float*)d_out;

    __bf16* Ebf   = (__bf16*)d_ws;                              // 4 MiB
    float*  s_arr = (float*)((char*)d_ws + (size_t)NROWS * DIM * 2);
    float*  r_arr = s_arr + NROWS;

    hipMemsetAsync(out, 0, sizeof(float), stream);
    normalize_kernel<<<NROWS / 4, 256, 0, stream>>>(emb, Ebf, s_arr, r_arr);
    loss_kernel<<<dim3(64, 64), 256, 0, stream>>>(Ebf, s_arr, r_arr, lab, out);
}

// Round 3
// 110.136 us; speedup vs baseline: 1.3386x; 1.3386x over previous
//
#include <hip/hip_runtime.h>
#include <hip/hip_bf16.h>

#define NROWS 8192
#define DIM   256
#define EPSV  1e-6f
#define BM    128
#define BN    128
#define BK    32
#define BKP   40   // padded LDS leading dim (+16 B) to spread bank groups

typedef __bf16 bf16x8 __attribute__((ext_vector_type(8)));
typedef float  f32x4  __attribute__((ext_vector_type(4)));

// ---------------------------------------------------------------------------
// Kernel 1: row-normalize, emit bf16(e) + P[i] = s + 2eps*r + d*eps^2/2,
//                                     Q[i] = s - 2eps*r + d*eps^2/2
// so that dist2(i,j) = P[i] + Q[j] - 2*G[i][j]. Also zero-inits out[0].
// One wave (64 lanes) per row; lane handles 4 consecutive floats.
// ---------------------------------------------------------------------------
__global__ __launch_bounds__(256) void normalize_kernel(
    const float* __restrict__ emb, __bf16* __restrict__ Ebf,
    float* __restrict__ P_out, float* __restrict__ Q_out,
    float* __restrict__ out)
{
    if (blockIdx.x == 0 && threadIdx.x == 0) out[0] = 0.0f;

    const int wave = threadIdx.x >> 6;
    const int lane = threadIdx.x & 63;
    const int row  = blockIdx.x * 4 + wave;

    const float4 v = ((const float4*)(emb + row * DIM))[lane];
    float ss = v.x*v.x + v.y*v.y + v.z*v.z + v.w*v.w;
    #pragma unroll
    for (int off = 32; off; off >>= 1) ss += __shfl_xor(ss, off);

    const float inv = 1.0f / fmaxf(sqrtf(ss), EPSV);
    float4 e; e.x = v.x*inv; e.y = v.y*inv; e.z = v.z*inv; e.w = v.w*inv;

    float sp = e.x*e.x + e.y*e.y + e.z*e.z + e.w*e.w;
    float rp = e.x + e.y + e.z + e.w;
    #pragma unroll
    for (int off = 32; off; off >>= 1) {
        sp += __shfl_xor(sp, off);
        rp += __shfl_xor(rp, off);
    }

    union { __bf16 h[4]; uint2 u; } pk;
    pk.h[0] = (__bf16)e.x; pk.h[1] = (__bf16)e.y;
    pk.h[2] = (__bf16)e.z; pk.h[3] = (__bf16)e.w;
    *(uint2*)(Ebf + row * DIM + lane * 4) = pk.u;

    if (lane == 0) {
        const float c = 0.5f * (float)DIM * EPSV * EPSV;
        P_out[row] = sp + 2.0f * EPSV * rp + c;
        Q_out[row] = sp - 2.0f * EPSV * rp + c;
    }
}

// ---------------------------------------------------------------------------
// Kernel 2: triangular 1D grid of 128x128 MFMA tiles (2080 blocks, bj<=bi),
// VGPR-staged LDS tiles (padded, conflict-spread), fused branch-lean loss
// epilogue, block reduce, one atomicAdd per block.
// ---------------------------------------------------------------------------
__global__ __launch_bounds__(256) void loss_kernel(
    const __bf16* __restrict__ Ebf,
    const float* __restrict__ P_arr, const float* __restrict__ Q_arr,
    const int* __restrict__ lab, float* __restrict__ out)
{
    // decode linear block id -> (bi, bj), bj <= bi
    const int t = blockIdx.x;
    int bi = (int)((sqrtf(8.0f * (float)t + 1.0f) - 1.0f) * 0.5f);
    while ((bi + 1) * (bi + 2) / 2 <= t) ++bi;
    while (bi * (bi + 1) / 2 > t) --bi;
    const int bj = t - bi * (bi + 1) / 2;
    const bool diag = (bi == bj);

    __shared__ __align__(16) __bf16 As[BM * BKP];
    __shared__ __align__(16) __bf16 Bs[BN * BKP];
    __shared__ float sP[BM], sQ[BN];
    __shared__ int   lI[BM], lJ[BN];
    __shared__ float wsum[4];

    const int tid  = threadIdx.x;
    const int wave = tid >> 6;
    const int lane = tid & 63;
    const int i0 = bi * BM, j0 = bj * BN;

    if (tid < 128) {
        sP[tid] = P_arr[i0 + tid]; lI[tid] = lab[i0 + tid];
        sQ[tid] = Q_arr[j0 + tid]; lJ[tid] = lab[j0 + tid];
    }

    f32x4 acc[4][4] = {};           // acc[fa][fb]: 4x4 frags of 16x16 per wave
    const int wm = wave >> 1, wn = wave & 1;
    const int quad = lane >> 4, mlane = lane & 15;

    #pragma unroll 1
    for (int kt = 0; kt < DIM / BK; ++kt) {
        const int k0 = kt * BK;
        // stage A/B tiles: 512 chunks of 8 bf16 each; thread does chunks tid, tid+256
        #pragma unroll
        for (int rr = 0; rr < 2; ++rr) {
            const int c   = tid + rr * 256;
            const int row = c >> 2;
            const int col = (c & 3) * 8;
            *(uint4*)(As + row * BKP + col) =
                *(const uint4*)(Ebf + (size_t)(i0 + row) * DIM + k0 + col);
            *(uint4*)(Bs + row * BKP + col) =
                *(const uint4*)(Ebf + (size_t)(j0 + row) * DIM + k0 + col);
        }
        __syncthreads();

        bf16x8 af[4], bfr[4];
        #pragma unroll
        for (int f = 0; f < 4; ++f) {
            af[f]  = *(const bf16x8*)(As + (wm * 64 + f * 16 + mlane) * BKP + quad * 8);
            bfr[f] = *(const bf16x8*)(Bs + (wn * 64 + f * 16 + mlane) * BKP + quad * 8);
        }
        #pragma unroll
        for (int fa = 0; fa < 4; ++fa)
            #pragma unroll
            for (int fb = 0; fb < 4; ++fb)
                acc[fa][fb] = __builtin_amdgcn_mfma_f32_16x16x32_bf16(
                    af[fa], bfr[fb], acc[fa][fb], 0, 0, 0);
        __syncthreads();
    }

    // Epilogue. C/D layout (m89/m91): col = lane&15, row = (lane>>4)*4 + reg
    float qv[4]; int lv[4], gjv[4];
    #pragma unroll
    for (int fb = 0; fb < 4; ++fb) {
        const int jl = wn * 64 + fb * 16 + mlane;
        qv[fb]  = sQ[jl];
        lv[fb]  = lJ[jl];
        gjv[fb] = j0 + jl;
    }

    float lsum = 0.0f;
    #pragma unroll
    for (int fa = 0; fa < 4; ++fa) {
        #pragma unroll
        for (int reg = 0; reg < 4; ++reg) {
            const int il = wm * 64 + fa * 16 + quad * 4 + reg;
            const int gi = i0 + il;
            const float pi = sP[il];
            const int   li = lI[il];
            #pragma unroll
            for (int fb = 0; fb < 4; ++fb) {
                const float g  = acc[fa][fb][reg];
                const float d2 = __builtin_fmaf(-2.0f, g, pi + qv[fb]);
                const float d  = __builtin_amdgcn_sqrtf(fmaxf(d2, 1e-12f));
                const bool same = (li == lv[fb]);
                float tt = same ? (d - 0.1f) : (1.0f - d);
                tt = fmaxf(tt, 0.0f);
                // boost=2 only on neg pairs with i==j+1 && lab[i]==1
                const float w = same ? 0.5f
                                     : ((gi == gjv[fb] + 1 && li == 1) ? 1.0f : 0.5f);
                float contrib = w * tt * tt;
                if (diag) contrib = (gi > gjv[fb]) ? contrib : 0.0f;
                lsum += contrib;
            }
        }
    }

    #pragma unroll
    for (int off = 32; off; off >>= 1) lsum += __shfl_down(lsum, off);
    if (lane == 0) wsum[wave] = lsum;
    __syncthreads();
    if (tid == 0) {
        const float bs = wsum[0] + wsum[1] + wsum[2] + wsum[3];
        const float scale = 1.0f / 33550336.0f;   // n*(n-1)/2 = 8192*8191/2
        atomicAdd(out, bs * scale);
    }
}

// ---------------------------------------------------------------------------
extern "C" void kernel_launch(void* const* d_in, const int* in_sizes, int n_in,
                              void* d_out, int out_size, void* d_ws, size_t ws_size,
                              hipStream_t stream)
{
    const float* emb = (const float*)d_in[0];
    const int*   lab = (const int*)d_in[1];
    float*       out = (float*)d_out;

    __bf16* Ebf   = (__bf16*)d_ws;                              // 4 MiB
    float*  P_arr = (float*)((char*)d_ws + (size_t)NROWS * DIM * 2);
    float*  Q_arr = P_arr + NROWS;

    normalize_kernel<<<NROWS / 4, 256, 0, stream>>>(emb, Ebf, P_arr, Q_arr, out);
    loss_kernel<<<64 * 65 / 2, 256, 0, stream>>>(Ebf, P_arr, Q_arr, lab, out);
}